// Round 7
// baseline (257.149 us; speedup 1.0000x reference)
//
#include <hip/hip_runtime.h>

#define B_     64
#define DIM_   384
#define RES_   14
#define N_     196
#define HEADS_ 8
#define KD_    32
#define D_     128
#define DH_    1024
#define QK_    256
#define CH_    1536
#define EPS_   1e-5f
#define SCALE_ 0.17677669529663687f   // 32^-0.5

typedef unsigned short u16;
typedef unsigned int u32;
typedef short v8s __attribute__((ext_vector_type(8)));
typedef float v4f __attribute__((ext_vector_type(4)));
typedef u16  v4u __attribute__((ext_vector_type(4)));
typedef u32  v2u __attribute__((ext_vector_type(2)));
typedef _Float16 h2 __attribute__((ext_vector_type(2)));

static __device__ __forceinline__ u16 f2bf(float f) {
    unsigned int u = __builtin_bit_cast(unsigned int, f);
    u = (u + 0x7fffu + ((u >> 16) & 1u)) >> 16;
    return (u16)u;
}
static __device__ __forceinline__ float bf2f(u16 u) {
    unsigned int x = ((unsigned int)u) << 16;
    return __builtin_bit_cast(float, x);
}

// workspace layout (u16 element offsets)
// GEMM operand images: [kstep][kquad(4)][row(128)][8] = 4096 elems (8KB)/kstep
#define WBI_OFF  0u          // Wb  image: 12 mtiles x 12 ksteps      (589824)
#define WPI_OFF  589824u     // wp  image: 3 mtiles x 32 ksteps       (393216)
#define QI_OFF   983040u     // qT  [B][8][256][32]                   (4194304)
#define KI_OFF   5177344u    // kT  [B][8][256][32]                   (4194304)
#define VI_OFF   9371648u    // v   image: [B][8] x 7 ksteps          (14680064)
#define VLOC_U16 53411840u   // vlocI in aoI image layout             (16777216)
#define TAIL_OFF 79101952u   // union: xI (6291456) / aoI (16777216)
#define TB_OFF   98770944u   // BN tables fp32[5888]
#define BIASE_OFF 98785920u  // biasE [196][8][196] fp32 (614656 u16)

// ---------------------------------------------------------------------------
// barrier-free direct-from-global 128x128 MFMA core.
// ---------------------------------------------------------------------------
template<int KSTEPS>
static __device__ __forceinline__ void gemm_direct(
    const u16* __restrict__ Ag, const u16* __restrict__ Bg,
    v4f acc[4][4], int tid)
{
    const int lane = tid & 63, w = tid >> 6;
    const int wm = (w & 1) * 64, wn = (w >> 1) * 64;
    const int quad = lane >> 4, l16 = lane & 15;
    const u16* pa = Ag + quad * 1024 + (wm + l16) * 8;
    const u16* pb = Bg + quad * 1024 + (wn + l16) * 8;
    v8s a[2][4], b[2][4];
    #pragma unroll
    for (int i = 0; i < 4; i++) {
        a[0][i] = *(const v8s*)(pa + i * 128);
        b[0][i] = *(const v8s*)(pb + i * 128);
    }
    #pragma unroll
    for (int ks = 0; ks < KSTEPS; ks++) {
        const int cur = ks & 1, nxt = cur ^ 1;
        if (ks + 1 < KSTEPS) {
            const u16* qa = pa + (size_t)(ks + 1) * 4096;
            const u16* qb = pb + (size_t)(ks + 1) * 4096;
            #pragma unroll
            for (int i = 0; i < 4; i++) {
                a[nxt][i] = *(const v8s*)(qa + i * 128);
                b[nxt][i] = *(const v8s*)(qb + i * 128);
            }
        }
        #pragma unroll
        for (int i = 0; i < 4; i++)
            #pragma unroll
            for (int j = 0; j < 4; j++)
                acc[i][j] = __builtin_amdgcn_mfma_f32_16x16x32_bf16(a[cur][i], b[cur][j], acc[i][j], 0, 0, 0);
    }
}

// 3-deep variant for long-K latency-exposed GEMMs (k_proj: K=32 steps).
template<int KSTEPS>
static __device__ __forceinline__ void gemm_direct3(
    const u16* __restrict__ Ag, const u16* __restrict__ Bg,
    v4f acc[4][4], int tid)
{
    const int lane = tid & 63, w = tid >> 6;
    const int wm = (w & 1) * 64, wn = (w >> 1) * 64;
    const int quad = lane >> 4, l16 = lane & 15;
    const u16* pa = Ag + quad * 1024 + (wm + l16) * 8;
    const u16* pb = Bg + quad * 1024 + (wn + l16) * 8;
    v8s a[3][4], b[3][4];
    #pragma unroll
    for (int s = 0; s < 2; s++) {
        #pragma unroll
        for (int i = 0; i < 4; i++) {
            a[s][i] = *(const v8s*)(pa + (size_t)s * 4096 + i * 128);
            b[s][i] = *(const v8s*)(pb + (size_t)s * 4096 + i * 128);
        }
    }
    #pragma unroll
    for (int ks = 0; ks < KSTEPS; ks++) {
        const int cur = ks % 3, nxt = (ks + 2) % 3;
        if (ks + 2 < KSTEPS) {
            const u16* qa = pa + (size_t)(ks + 2) * 4096;
            const u16* qb = pb + (size_t)(ks + 2) * 4096;
            #pragma unroll
            for (int i = 0; i < 4; i++) {
                a[nxt][i] = *(const v8s*)(qa + i * 128);
                b[nxt][i] = *(const v8s*)(qb + i * 128);
            }
        }
        #pragma unroll
        for (int i = 0; i < 4; i++)
            #pragma unroll
            for (int j = 0; j < 4; j++)
                acc[i][j] = __builtin_amdgcn_mfma_f32_16x16x32_bf16(a[cur][i], b[cur][j], acc[i][j], 0, 0, 0);
    }
}

// ---------------------------------------------------------------------------
// k_pre: ALL preprocessing in one launch.
// ---------------------------------------------------------------------------
__global__ __launch_bounds__(256) void k_pre(
    const float* __restrict__ x,
    const float* __restrict__ wq, const float* __restrict__ wk,
    const float* __restrict__ wv, const float* __restrict__ wp,
    const float* __restrict__ ab,
    const float* __restrict__ th1w, const float* __restrict__ th1b,
    const float* __restrict__ bq, const float* __restrict__ bnq,
    const float* __restrict__ bk, const float* __restrict__ bnk,
    const float* __restrict__ bv, const float* __restrict__ bnv,
    const float* __restrict__ bp, const float* __restrict__ bnp,
    const float* __restrict__ bvl, const float* __restrict__ bnvl,
    const int* __restrict__ bidx,
    u16* __restrict__ xI, u16* __restrict__ WbI, u16* __restrict__ WpI,
    float* __restrict__ TB, float* __restrict__ biasE)
{
    __shared__ float T[64][65];
    const int tid = threadIdx.x;
    if (blockIdx.x < 1536) {      // ---- castX ----
        const int t  = blockIdx.x;
        const int n0 = (t & 3) * 64;
        const int k0 = ((t >> 2) % 6) * 64;
        const int b  = t / 24;
        const int c = tid & 63, r4 = tid >> 6;
        #pragma unroll
        for (int i = 0; i < 16; i++) {
            int kr = i * 4 + r4;
            int gn = n0 + c;
            T[kr][c] = (gn < N_) ? x[((size_t)b * DIM_ + k0 + kr) * N_ + gn] : 0.f;
        }
        __syncthreads();
        #pragma unroll
        for (int it = 0; it < 16; it++) {
            int j = it * 256 + tid;
            int kk = j & 63, nn = j >> 6;
            int k = k0 + kk, n = n0 + nn;
            xI[(size_t)b * 98304 + (n >> 7) * 49152 + (k >> 5) * 4096
               + ((k >> 3) & 3) * 1024 + (n & 127) * 8 + (k & 7)] = f2bf(T[kk][nn]);
        }
        return;
    }
    int i = (blockIdx.x - 1536) * 256 + tid;
    if (i < 589824) {           // qkv weight image
        int mt = i / 49152, rem = i % 49152;
        int ks = rem >> 12, r2 = rem & 4095;
        int q = r2 >> 10, row = (r2 >> 3) & 127, e = r2 & 7;
        int c = mt * 128 + row, k = ks * 32 + q * 8 + e;
        float v = (c < 256) ? wq[c * 384 + k]
                : (c < 512) ? wk[(c - 256) * 384 + k]
                            : wv[(size_t)(c - 512) * 384 + k];
        WbI[i] = f2bf(v);
    } else if (i < 983040) {    // proj weight image
        int j = i - 589824;
        int mt = j >> 17, rem = j & 131071;
        int ks = rem >> 12, r2 = rem & 4095;
        int q = r2 >> 10, row = (r2 >> 3) & 127, e = r2 & 7;
        int p = mt * 128 + row, k = ks * 32 + q * 8 + e;
        WpI[j] = f2bf(wp[(size_t)p * 1024 + k]);
    } else if (i < 985984) {    // BN tables
        int j = i - 983040;
        if (j < 256) {
            int c = j;
            float s = bnq[c] * rsqrtf(bnq[768 + c] + EPS_);
            float t = (bq[c] - bnq[512 + c]) * s + bnq[256 + c];
            TB[c] = s * SCALE_; TB[256 + c] = t * SCALE_;
        } else if (j < 512) {
            int c = j - 256;
            float s = bnk[c] * rsqrtf(bnk[768 + c] + EPS_);
            float t = (bk[c] - bnk[512 + c]) * s + bnk[256 + c];
            TB[512 + c] = s; TB[768 + c] = t;
        } else if (j < 1536) {
            int c = j - 512;
            float s = bnv[c] * rsqrtf(bnv[3072 + c] + EPS_);
            float t = (bv[c] - bnv[2048 + c]) * s + bnv[1024 + c];
            TB[1024 + c] = s; TB[2048 + c] = t;
        } else if (j < 1920) {
            int c = j - 1536;
            float s = bnp[c] * rsqrtf(bnp[1152 + c] + EPS_);
            float t = (bp[c] - bnp[768 + c]) * s + bnp[384 + c];
            TB[3072 + c] = s; TB[3456 + c] = t;
        } else {
            int c = j - 1920;
            float s = bnvl[c] * rsqrtf(bnvl[3072 + c] + EPS_);
            float t = (bvl[c] - bnvl[2048 + c]) * s + bnvl[1024 + c];
            TB[3840 + c] = s; TB[4864 + c] = t;
        }
    } else if (i < 1293312) {   // biasE[n][o][m] = th1-folded bias - 5
        int j = i - 985984;
        int m = j % N_;
        int t = j / N_;
        int o = t & 7;
        int n = t >> 3;
        int idx = bidx[n * N_ + m];
        float a = th1b[o];
        #pragma unroll
        for (int h = 0; h < 8; h++) a += th1w[o * 8 + h] * ab[h * N_ + idx];
        biasE[j] = a - 5.f;
    }
}

// ---------------------------------------------------------------------------
// K1: QKV GEMM (direct core).
// XCD swizzle: 1536 blocks = 8 XCDs x (8 b x 24 tiles).
// ---------------------------------------------------------------------------
__global__ __launch_bounds__(256) void k_qkv(
    const u16* __restrict__ WbI, const u16* __restrict__ xI,
    const float* __restrict__ TB,
    u16* __restrict__ qI, u16* __restrict__ kI, u16* __restrict__ vI)
{
    const int tid = threadIdx.x;
    const int L = blockIdx.x + 2 * (blockIdx.y + 12 * blockIdx.z);
    const int idx = L >> 3;                 // 0..191
    const int b  = (L & 7) * 8 + idx / 24;  // contiguous b-chunk per XCD
    const int r  = idx % 24;
    const int mt = r >> 1, nt = r & 1;
    v4f acc[4][4] = {};
    gemm_direct<12>(WbI + (size_t)mt * 49152,
                    xI + ((size_t)b * 2 + nt) * 49152, acc, tid);

    const int lane = tid & 63, w = tid >> 6;
    const int wm = (w & 1) * 64, wn = (w >> 1) * 64;
    const int quad = lane >> 4, l16 = lane & 15;
    #pragma unroll
    for (int i = 0; i < 4; i++) {
        #pragma unroll
        for (int j = 0; j < 4; j++) {
            int gc = mt * 128 + wm + i * 16 + quad * 4;  // global channel base
            int n  = nt * 128 + wn + j * 16 + l16;       // token (0..255)
            v4f v = acc[i][j];
            if (gc < 256) {            // q
                v4f s = *(const v4f*)&TB[gc];
                v4f t = *(const v4f*)&TB[256 + gc];
                v4u u;
                #pragma unroll
                for (int r2 = 0; r2 < 4; r2++) u[r2] = f2bf(v[r2] * s[r2] + t[r2]);
                *(v4u*)&qI[((size_t)(b * 8 + (gc >> 5)) * 256 + n) * 32 + (gc & 31)] = u;
            } else if (gc < 512) {     // k
                int c = gc - 256;
                v4f s = *(const v4f*)&TB[512 + c];
                v4f t = *(const v4f*)&TB[768 + c];
                v4u u;
                #pragma unroll
                for (int r2 = 0; r2 < 4; r2++) u[r2] = f2bf(v[r2] * s[r2] + t[r2]);
                *(v4u*)&kI[((size_t)(b * 8 + (c >> 5)) * 256 + n) * 32 + (c & 31)] = u;
            } else {                   // v -> image (row = e, col = n as k-dim)
                int c = gc - 512;      // 0..1023
                if (n < 224) {
                    int o = c >> 7, e = c & 127;
                    u16* base = vI + ((size_t)(b * 8 + o) * 7 + (n >> 5)) * 4096
                                + ((n >> 3) & 3) * 1024 + (n & 7);
                    #pragma unroll
                    for (int r2 = 0; r2 < 4; r2++) {
                        u16 outv = 0;
                        if (n < N_) outv = f2bf(v[r2] * TB[1024 + c + r2] + TB[2048 + c + r2]);
                        base[(e + r2) * 8] = outv;
                    }
                }
            }
        }
    }
}

// ---------------------------------------------------------------------------
// K2: depthwise 3x3 conv. Block = 64 channels of one (b,o).
// ---------------------------------------------------------------------------
__global__ __launch_bounds__(256) void k_dwconv(
    const u16* __restrict__ vI, const float* __restrict__ wvl,
    const float* __restrict__ TB, u16* __restrict__ vlocI)
{
    __shared__ u16 V[64 * 230];             // 29440 B
    const int tid = threadIdx.x;
    const int sub = blockIdx.x;             // 0..15: o = sub>>1, half = sub&1
    const int b   = blockIdx.y;
    const int o   = sub >> 1;
    const int e0  = (sub & 1) * 64;
    const u16* img = vI + (size_t)(b * 8 + o) * 28672;

    {
        const int quad = tid >> 6, l = tid & 63;
        #pragma unroll
        for (int i = 0; i < 7; i++) {
            v8s u = *(const v8s*)&img[i * 4096 + quad * 1024 + (e0 + l) * 8];
            const u32* ui = (const u32*)&u;
            int m0 = i * 32 + quad * 8;
            u32* dst = (u32*)&V[l * 230 + m0];
            #pragma unroll
            for (int c = 0; c < 4; c++) dst[c] = ui[c];
        }
    }
    __syncthreads();

    const int e = tid & 63, j = tid >> 6;
    const int cg = sub * 64 + e;
    const int y0 = j * 4;
    const int ny = (j == 3) ? 2 : 4;
    float wgt[9];
    #pragma unroll
    for (int k = 0; k < 9; k++) wgt[k] = wvl[cg * 9 + k];
    const float sc = TB[3840 + cg], sh = TB[4864 + cg];
    u32 po[4][7];

    for (int yi = 0; yi < ny; yi++) {
        int y = y0 + yi;
        float a[3][16];
        #pragma unroll
        for (int dy = 0; dy < 3; dy++) {
            int yy = y + dy - 1;
            a[dy][0] = 0.f; a[dy][15] = 0.f;
            if (yy < 0 || yy > 13) {
                #pragma unroll
                for (int x = 1; x < 15; x++) a[dy][x] = 0.f;
            } else {
                const u16* rp = &V[e * 230 + yy * 14];
                #pragma unroll
                for (int c4 = 0; c4 < 7; c4++) {
                    u32 u = *(const u32*)&rp[c4 * 2];
                    a[dy][1 + 2 * c4] = bf2f((u16)(u & 0xffffu));
                    a[dy][2 + 2 * c4] = bf2f((u16)(u >> 16));
                }
            }
        }
        #pragma unroll
        for (int xp = 0; xp < 7; xp++) {
            u32 pk = 0;
            #pragma unroll
            for (int half = 0; half < 2; half++) {
                int x = 2 * xp + half;
                float s = 0.f;
                #pragma unroll
                for (int dy = 0; dy < 3; dy++)
                    #pragma unroll
                    for (int kx = 0; kx < 3; kx++)
                        s += wgt[dy * 3 + kx] * a[dy][x + kx];
                u16 bv = f2bf(s * sc + sh);
                pk |= ((u32)bv) << (16 * half);
            }
            po[yi][xp] = pk;
        }
    }
    __syncthreads();

    for (int yi = 0; yi < ny; yi++) {
        u32* dst = (u32*)&V[e * 196 + (y0 + yi) * 14];
        #pragma unroll
        for (int xp = 0; xp < 7; xp++) dst[xp] = po[yi][xp];
    }
    __syncthreads();

    for (int it = 0; it < 7; it++) {
        int idx = it * 256 + tid;
        if (idx < 1568) {
            int g = idx / 196, n = idx - g * 196;
            v4u lo, hi;
            #pragma unroll
            for (int r = 0; r < 4; r++) lo[r] = V[(g * 8 + r) * 196 + n];
            #pragma unroll
            for (int r = 0; r < 4; r++) hi[r] = V[(g * 8 + 4 + r) * 196 + n];
            u16* dst = vlocI + ((size_t)(b * 2 + (n >> 7)) * 32 + sub * 2 + (g >> 2)) * 4096
                     + (g & 3) * 1024 + (n & 127) * 8;
            *(v4u*)dst = lo;
            *(v4u*)(dst + 4) = hi;
        }
    }
}

// ---------------------------------------------------------------------------
// K3: FUSED attention + AV + vloc + relu -> aoI. 512 threads / 8 waves,
// QBLK=16, register-resident softmax state:
//   A:  wave w computes mtiles {w, w+8} (waves 5-7: {w}) for ALL 8 heads;
//       lane (q=l16, quad) owns all-h S for its 4 m -> th1-mix + exp in
//       registers; E packed f16 (32 VGPR).
//   B2: shfl_xor(16/32) + 4KB LDS cross-wave reduce -> invS; fold into E.
//   C:  8-iteration o-loop: th2-mix writes a P-slice [16q][232m] bf16
//       (stride 464B = 116 dw, 116%32=20 -> 2-way-max bank aliasing, free),
//       double-buffered; all 7 V fragments issued BEFORE the barrier; then
//       clean 7-step MFMA chain; invalid m in [196,208) written as zeros,
//       m>=208 (ks=6, quad>=2) uses a shared zero fragment.
// LDS ~19.0 KB -> >=3 blocks/CU co-resident.
// XCD swizzle: 832 blocks = 8 XCDs x (8 b x 13 qt).
// ---------------------------------------------------------------------------
#define SLST 232   // P-slice m-stride in u16 (464 B row; %8==0 for 16B align)
__global__ __launch_bounds__(512, 4) void k_attn_av(
    const u16* __restrict__ qI, const u16* __restrict__ kI,
    const u16* __restrict__ vI,
    const float* __restrict__ th1w,
    const float* __restrict__ th2w, const float* __restrict__ th2b,
    const float* __restrict__ biasE,
    const u16* __restrict__ vlocI, u16* __restrict__ aoI)
{
    __shared__ __attribute__((aligned(16))) u16 Ps[2][16 * SLST];  // 2 x 7424 B
    __shared__ float red[8][8][16];           // [wave][o][q] 4096 B
    __shared__ float invS[8][16];             // [o][q] 512 B
    __shared__ __attribute__((aligned(16))) u16 Zf[8];   // zero fragment
    const int tid = threadIdx.x;
    const int w = tid >> 6, lane = tid & 63;
    const int quad = lane >> 4, l16 = lane & 15;
    const int L = blockIdx.x + 13 * blockIdx.y;
    const int idx = L >> 3;                 // 0..103
    const int b  = (L & 7) * 8 + idx / 13;  // contiguous b-chunk per XCD
    const int qt = idx % 13;                // 0..12
    const int n0 = qt * 16;
    if (tid < 8) Zf[tid] = 0;

    const int nmt = (w < 5) ? 2 : 1;        // waves 0-4: mtiles {w, w+8}; 5-7: {w}
    const int nq  = n0 + l16;               // this lane's q token
    const int nb  = (nq < N_) ? nq : 0;     // clamped biasE row
    const float* bErow = biasE + (size_t)nb * 1568;

    // ---- phase A + B1: S via MFMA (all 8 h per mtile), th1-mix + exp in regs
    h2 E[2][8][2] = {};     // [mi][o][pair]; pair p covers m r={2p,2p+1}
    #pragma unroll
    for (int mi = 0; mi < 2; mi++) {
        if (mi >= nmt) break;
        const int mt = w + mi * 8;
        v4f S[8];
        const u16* qb0 = qI + (size_t)b * 8 * 8192;
        const u16* kb0 = kI + (size_t)b * 8 * 8192;
        #pragma unroll
        for (int h = 0; h < 8; h++) {
            v8s qf = *(const v8s*)&qb0[h * 8192 + (n0 + l16) * 32 + quad * 8];
            v8s kf = *(const v8s*)&kb0[h * 8192 + (mt * 16 + l16) * 32 + quad * 8];
            v4f z = {};
            S[h] = __builtin_amdgcn_mfma_f32_16x16x32_bf16(kf, qf, z, 0, 0, 0);
        }
        const bool mvalid = (mt < 12) || (quad == 0);   // all 4 m < 196 ?
        const int mb = mt * 16 + quad * 4;
        if (mvalid) {
            #pragma unroll
            for (int o = 0; o < 8; o++) {
                v4f a = *(const v4f*)&bErow[o * 196 + mb];
                #pragma unroll
                for (int h = 0; h < 8; h++) {
                    float t1 = th1w[o * 8 + h];
                    #pragma unroll
                    for (int r = 0; r < 4; r++) a[r] += t1 * S[h][r];
                }
                E[mi][o][0] = h2{(_Float16)__expf(a[0]), (_Float16)__expf(a[1])};
                E[mi][o][1] = h2{(_Float16)__expf(a[2]), (_Float16)__expf(a[3])};
            }
        }
    }

    // ---- B2: softmax denominators per (o, q) ----
    {
        float psum[8];
        #pragma unroll
        for (int o = 0; o < 8; o++) {
            float s = (float)E[0][o][0].x + (float)E[0][o][0].y
                    + (float)E[0][o][1].x + (float)E[0][o][1].y
                    + (float)E[1][o][0].x + (float)E[1][o][0].y
                    + (float)E[1][o][1].x + (float)E[1][o][1].y;
            s += __shfl_xor(s, 16, 64);
            s += __shfl_xor(s, 32, 64);
            psum[o] = s;
        }
        red[w][quad * 2 + 0][l16] = psum[quad * 2 + 0];
        red[w][quad * 2 + 1][l16] = psum[quad * 2 + 1];
    }
    __syncthreads();
    if (tid < 128) {
        int o = tid >> 4, q = tid & 15;
        float s = 0.f;
        #pragma unroll
        for (int wv = 0; wv < 8; wv++) s += red[wv][o][q];
        invS[o][q] = 1.f / s;
    }
    __syncthreads();

    // fold invS into E (packed f16 mul)
    #pragma unroll
    for (int o = 0; o < 8; o++) {
        float is = invS[o][l16];
        h2 is2 = h2{(_Float16)is, (_Float16)is};
        E[0][o][0] *= is2; E[0][o][1] *= is2;
        E[1][o][0] *= is2; E[1][o][1] *= is2;
    }

    // ---- C-loop over output heads: B3 slice write + AV MFMA + epilogue ----
    const int half_ = n0 >> 7;
    const int row0 = n0 & 127;
    const bool act = (nq < N_);
    char* psrow0 = (char*)&Ps[0][0] + l16 * (SLST * 2);
    char* psrow1 = (char*)&Ps[1][0] + l16 * (SLST * 2);

    #pragma unroll
    for (int o2 = 0; o2 < 8; o2++) {
        char* psb = (o2 & 1) ? psrow1 : psrow0;
        // B3: P[o2] for this lane's m-chunks; zeros for invalid m (196..208)
        #pragma unroll
        for (int mi = 0; mi < 2; mi++) {
            if (mi >= nmt) break;
            const int mt = w + mi * 8;
            const bool mvalid = (mt < 12) || (quad == 0);
            u32 pk0 = 0, pk1 = 0;
            if (mvalid) {
                float p0 = th2b[o2], p1 = th2b[o2], p2 = th2b[o2], p3 = th2b[o2];
                #pragma unroll
                for (int o = 0; o < 8; o++) {
                    float wgt = th2w[o2 * 8 + o];
                    p0 += wgt * (float)E[mi][o][0].x;
                    p1 += wgt * (float)E[mi][o][0].y;
                    p2 += wgt * (float)E[mi][o][1].x;
                    p3 += wgt * (float)E[mi][o][1].y;
                }
                pk0 = (u32)f2bf(p0) | ((u32)f2bf(p1) << 16);
                pk1 = (u32)f2bf(p2) | ((u32)f2bf(p3) << 16);
            }
            v2u pw; pw[0] = pk0; pw[1] = pk1;
            *(v2u*)(psb + mt * 32 + quad * 8) = pw;   // in-bounds: <= 416 < 464
        }
        // issue ALL 7 V fragments before the barrier (fly during the drain)
        const u16* vb = vI + (size_t)(b * 8 + o2) * 28672;
        const u16* af = vb + quad * 1024 + (w * 16 + l16) * 8;
        v8s va[7];
        #pragma unroll
        for (int ks = 0; ks < 7; ks++)
            va[ks] = *(const v8s*)(af + (size_t)ks * 4096);
        __syncthreads();

        // AV: wave w -> e-rows w*16..+15 of head o2
        v4f acc = {};
        __builtin_amdgcn_s_setprio(1);
        #pragma unroll
        for (int ks = 0; ks < 7; ks++) {
            v8s bfr = (ks == 6 && quad >= 2)
                    ? *(const v8s*)&Zf[0]                       // m >= 208
                    : *(const v8s*)(psb + ks * 64 + quad * 16); // <= 415 in-row
            acc = __builtin_amdgcn_mfma_f32_16x16x32_bf16(va[ks], bfr, acc, 0, 0, 0);
        }
        __builtin_amdgcn_s_setprio(0);

        // epilogue for (o2, e-block w)
        if (act) {
            const int c0 = o2 * 128 + w * 16 + quad * 4;
            const size_t ioff = ((size_t)(b * 2 + half_) * 32 + (c0 >> 5)) * 4096
                              + ((c0 >> 3) & 3) * 1024 + (size_t)(row0 + l16) * 8 + (c0 & 7);
            v4u lv = *(const v4u*)&vlocI[ioff];
            v4u u;
            #pragma unroll
            for (int r = 0; r < 4; r++)
                u[r] = f2bf(fmaxf(acc[r] + bf2f(lv[r]), 0.f));
            *(v4u*)&aoI[ioff] = u;
        }
    }
}

// ---------------------------------------------------------------------------
// K6: projection GEMM (3-deep direct core, K=1024) + BN -> out fp32
// XCD swizzle: 384 blocks = 8 XCDs x (8 b x 6 tiles).
// ---------------------------------------------------------------------------
__global__ __launch_bounds__(256) void k_proj(
    const u16* __restrict__ WpI, const u16* __restrict__ aoI,
    const float* __restrict__ TB, float* __restrict__ out)
{
    const int tid = threadIdx.x;
    const int L = blockIdx.x + 2 * (blockIdx.y + 3 * blockIdx.z);
    const int idx = L >> 3;                 // 0..47
    const int b  = (L & 7) * 8 + idx / 6;   // contiguous b-chunk per XCD
    const int r  = idx % 6;
    const int mt = r >> 1, nt = r & 1;
    v4f acc[4][4] = {};
    gemm_direct3<32>(WpI + (size_t)mt * 131072,
                     aoI + ((size_t)b * 2 + nt) * 131072, acc, tid);

    const int lane = tid & 63, w = tid >> 6;
    const int wm = (w & 1) * 64, wn = (w >> 1) * 64;
    const int quad = lane >> 4, l16 = lane & 15;
    #pragma unroll
    for (int i = 0; i < 4; i++) {
        #pragma unroll
        for (int j = 0; j < 4; j++) {
            int p0 = mt * 128 + wm + i * 16 + quad * 4;
            int n  = nt * 128 + wn + j * 16 + l16;
            if (n < N_) {
                v4f s = *(const v4f*)&TB[3072 + p0];
                v4f t = *(const v4f*)&TB[3456 + p0];
                #pragma unroll
                for (int r2 = 0; r2 < 4; r2++)
                    out[((size_t)b * DIM_ + p0 + r2) * N_ + n] = acc[i][j][r2] * s[r2] + t[r2];
            }
        }
    }
}

// ---------------------------------------------------------------------------
extern "C" void kernel_launch(void* const* d_in, const int* in_sizes, int n_in,
                              void* d_out, int out_size, void* d_ws, size_t ws_size,
                              hipStream_t stream)
{
    const float* x    = (const float*)d_in[0];
    const float* wq   = (const float*)d_in[1];
    const float* bq   = (const float*)d_in[2];
    const float* bnq  = (const float*)d_in[3];
    const float* wk   = (const float*)d_in[4];
    const float* bk   = (const float*)d_in[5];
    const float* bnk  = (const float*)d_in[6];
    const float* wv   = (const float*)d_in[7];
    const float* bv   = (const float*)d_in[8];
    const float* bnv  = (const float*)d_in[9];
    const float* wvl  = (const float*)d_in[10];
    const float* bvl  = (const float*)d_in[11];
    const float* bnvl = (const float*)d_in[12];
    const float* th1w = (const float*)d_in[13];
    const float* th1b = (const float*)d_in[14];
    const float* th2w = (const float*)d_in[15];
    const float* th2b = (const float*)d_in[16];
    const float* wp   = (const float*)d_in[17];
    const float* bp   = (const float*)d_in[18];
    const float* bnp  = (const float*)d_in[19];
    const float* ab   = (const float*)d_in[20];
    const int*   bidx = (const int*)d_in[21];
    float* out = (float*)d_out;

    u16* wsb  = (u16*)d_ws;
    u16* WbI  = wsb + WBI_OFF;
    u16* WpI  = wsb + WPI_OFF;
    u16* qI   = wsb + QI_OFF;
    u16* kI   = wsb + KI_OFF;
    u16* vI   = wsb + VI_OFF;
    u16* vlocI = wsb + VLOC_U16;
    u16* xI   = wsb + TAIL_OFF;   // aliased: xI -> aoI (disjoint lifetimes)
    u16* aoI  = wsb + TAIL_OFF;
    float* TB    = (float*)(wsb + TB_OFF);
    float* biasE = (float*)(wsb + BIASE_OFF);

    k_pre<<<dim3(6588), 256, 0, stream>>>(x, wq, wk, wv, wp, ab, th1w, th1b,
                                          bq, bnq, bk, bnk, bv, bnv, bp, bnp, bvl, bnvl,
                                          bidx, xI, WbI, WpI, TB, biasE);
    k_qkv<<<dim3(2, 12, B_), 256, 0, stream>>>(WbI, xI, TB, qI, kI, vI);
    k_dwconv<<<dim3(16, B_), 256, 0, stream>>>(vI, wvl, TB, vlocI);
    k_attn_av<<<dim3(13, B_), 512, 0, stream>>>(qI, kI, vI, th1w, th2w, th2b,
                                                biasE, vlocI, aoI);
    k_proj<<<dim3(2, 3, B_), 256, 0, stream>>>(WpI, aoI, TB, out);
}